// Round 2
// baseline (335.080 us; speedup 1.0000x reference)
//
#include <hip/hip_runtime.h>

#define PP    32      // nodes per graph
#define FF    16      // input features
#define HH    4       // heads
#define CC    32      // head dim
#define DD    128     // hidden (H*C)
#define EDIM  5
#define EPG   992     // edges per graph = P*(P-1)
#define NB    512     // graphs

// ---- DPP helpers (validated R4: ctrl 0x111/2/4/8, 0x142) --------------------
template <int CTRL>
__device__ __forceinline__ float dpp_add(float v) {
    int t = __builtin_amdgcn_update_dpp(0, __builtin_bit_cast(int, v), CTRL, 0xF, 0xF, true);
    return v + __builtin_bit_cast(float, t);
}
template <int CTRL>
__device__ __forceinline__ float dpp_mov(float v) {
    int t = __builtin_amdgcn_update_dpp(0, __builtin_bit_cast(int, v), CTRL, 0xF, 0xF, true);
    return __builtin_bit_cast(float, t);
}
// full 64-lane sum -> result valid in lane 63
__device__ __forceinline__ float red64(float v) {
    v = dpp_add<0x111>(v);   // row_shr:1
    v = dpp_add<0x112>(v);   // row_shr:2
    v = dpp_add<0x114>(v);   // row_shr:4
    v = dpp_add<0x118>(v);   // row_shr:8
    v = dpp_add<0x142>(v);   // row_bcast:15
    v = dpp_add<0x143>(v);   // row_bcast:31
    return v;
}
// quad butterfly sum -> all 4 lanes hold the sum
__device__ __forceinline__ float redquad(float v) {
    v = dpp_add<0xB1>(v);    // quad_perm [1,0,3,2]  (xor 1)
    v = dpp_add<0x4E>(v);    // quad_perm [2,3,0,1]  (xor 2)
    return v;
}
// quad butterfly max -> all 4 lanes hold the max
__device__ __forceinline__ float maxquad(float v) {
    v = fmaxf(v, dpp_mov<0xB1>(v));
    v = fmaxf(v, dpp_mov<0x4E>(v));
    return v;
}
// xor-4 butterfly add via ds_swizzle (BitMode: xor=4, and=0x1F) -> 8-lane sum
__device__ __forceinline__ float swz_xor4_add(float v) {
    int t = __builtin_amdgcn_ds_swizzle(__builtin_bit_cast(int, v), 0x101F);
    return v + __builtin_bit_cast(float, t);
}

// ---- GATv2 layer (1024-thread block) ---------------------------------------
// Score phase lane map: s = tid>>5 (node), h = (tid>>3)&3 (head), c8 = tid&7
// (4-channel chunk); ch0 = (tid&31)*4.  Per lane: We slice (20 regs), att (4),
// xl (4) -> ~50 live VGPRs, fits the 64-reg tier for 8 waves/SIMD.
// Head-sum = quad DPP + ds_swizzle xor-4 (8-lane butterfly).
// Edge attrs loaded directly per lane (same-addr lanes broadcast in L1).
// Diagonal d==s computed with a clamped in-bounds edge and discarded by softmax.
// sS layout: sS[s*128 + d*4 + h].
__device__ __forceinline__ void attention(const float* __restrict__ eattr,
                                          const float* __restrict__ We, const float* __restrict__ att,
                                          const float* __restrict__ bias,
                                          const float* __restrict__ sMsg, const float* __restrict__ sDst,
                                          float* __restrict__ sS, float* __restrict__ sOut,
                                          int tid, long eBase, bool relu)
{
    {
        const int s   = tid >> 5;
        const int h4  = (tid >> 3) & 3;
        const int ch0 = (tid & 31) * 4;               // h*32 + c8*4
        float we[20], at[4], xl[4];
#pragma unroll
        for (int q = 0; q < 5; ++q)
            *(float4*)(we + q * 4) = *(const float4*)(We + ch0 * EDIM + q * 4);
        *(float4*)(at) = *(const float4*)(att + ch0);
        *(float4*)(xl) = *(const float4*)(sMsg + s * DD + ch0);

        for (int d = 0; d < PP; ++d) {
            int jj = d - (d > s);
            if (jj > 30) jj = 30;                     // d==s==31 clamp (discarded)
            const float* ea = eattr + (eBase + s * 31 + jj) * EDIM;
            const float e0 = ea[0], e1 = ea[1], e2 = ea[2], e3 = ea[3], e4 = ea[4];
            float xr[4];
            *(float4*)(xr) = *(const float4*)(sDst + d * DD + ch0);
            float acc0 = 0.f, acc1 = 0.f;
#pragma unroll
            for (int c = 0; c < 4; ++c) {
                float v = xl[c] + xr[c];
                const float* w = we + c * EDIM;
                v = fmaf(w[0], e0, v); v = fmaf(w[1], e1, v); v = fmaf(w[2], e2, v);
                v = fmaf(w[3], e3, v); v = fmaf(w[4], e4, v);
                v = fmaf(0.4f, fabsf(v), 0.6f * v);   // leaky_relu(., 0.2)
                if (c & 1) acc1 = fmaf(v, at[c], acc1);
                else       acc0 = fmaf(v, at[c], acc0);
            }
            float r = redquad(acc0 + acc1);           // sum within quad
            r = swz_xor4_add(r);                      // + partner quad -> 8-lane sum
            if ((tid & 7) == (d & 7))
                sS[s * DD + d * HH + h4] = r;
        }
    }
    __syncthreads();
    // ---- segment softmax over s != d per column (d*4+h): 512 threads,
    // quad per column, r = tid&3 owns 8 rows, DPP quad reduce.
    if (tid < 512) {
        const int col = tid >> 2;
        const int r   = tid & 3;
        const int dd  = col >> 2;                     // destination node of this column
        float v[8];
        float mx = -3.4e38f;
#pragma unroll
        for (int i = 0; i < 8; ++i) {
            const int s = r * 8 + i;
            v[i] = sS[s * DD + col];
            mx = (s == dd) ? mx : fmaxf(mx, v[i]);
        }
        mx = maxquad(mx);
        float sum = 0.f;
#pragma unroll
        for (int i = 0; i < 8; ++i) {
            const int s = r * 8 + i;
            float ex = __expf(v[i] - mx);
            ex = (s == dd) ? 0.f : ex;                // diagonal forced to 0
            v[i] = ex; sum += ex;
        }
        sum = redquad(sum);
        const float inv = 1.f / (sum + 1e-16f);
#pragma unroll
        for (int i = 0; i < 8; ++i)
            sS[(r * 8 + i) * DD + col] = v[i] * inv;
    }
    __syncthreads();
    // ---- aggregation (1024 threads): one (d, float4-column) per thread.
    // out[d][ch] = bias[ch] + sum_s alpha[s][d,h(ch)] * msg[s][ch]
    {
        const int d = tid >> 5, ch4 = tid & 31;
        const int idx = d * HH + (ch4 >> 3);
        float4 acc = *(const float4*)(bias + ch4 * 4);
#pragma unroll
        for (int s = 0; s < PP; ++s) {
            const float a = sS[s * DD + idx];         // alpha(d==s) == 0
            const float4 xv = *(const float4*)(sMsg + s * DD + ch4 * 4);
            acc.x = fmaf(a, xv.x, acc.x);
            acc.y = fmaf(a, xv.y, acc.y);
            acc.z = fmaf(a, xv.z, acc.z);
            acc.w = fmaf(a, xv.w, acc.w);
        }
        if (relu) {
            acc.x = fmaxf(acc.x, 0.f); acc.y = fmaxf(acc.y, 0.f);
            acc.z = fmaxf(acc.z, 0.f); acc.w = fmaxf(acc.w, 0.f);
        }
        *(float4*)(sOut + d * DD + ch4 * 4) = acc;
    }
}

extern "C" __global__ void __launch_bounds__(1024, 8)
planetwars_gnn_kernel(const float* __restrict__ x, const float* __restrict__ eattr,
                      const float* __restrict__ W1l, const float* __restrict__ b1l,
                      const float* __restrict__ W1r, const float* __restrict__ b1r,
                      const float* __restrict__ W1e, const float* __restrict__ att1, const float* __restrict__ bias1,
                      const float* __restrict__ W2l, const float* __restrict__ b2l,
                      const float* __restrict__ W2r, const float* __restrict__ b2r,
                      const float* __restrict__ W2e, const float* __restrict__ att2, const float* __restrict__ bias2,
                      const float* __restrict__ Wc1, const float* __restrict__ bc1,
                      const float* __restrict__ Wc2, const float* __restrict__ bc2,
                      const float* __restrict__ Ws1, const float* __restrict__ bs1,
                      const float* __restrict__ Ws2, const float* __restrict__ bs2,
                      const float* __restrict__ Wn1, const float* __restrict__ bn1,
                      const float* __restrict__ Wn2, const float* __restrict__ bn2,
                      float* __restrict__ out)
{
    __shared__ __align__(16) float sA[PP * DD];   // xl1 -> xl2
    __shared__ __align__(16) float sB[PP * DD];   // xr1 -> xr2
    __shared__ __align__(16) float sH[PP * DD];   // h1 -> h2
    __shared__ __align__(16) float sU[PP * DD];   // x | scores/alpha | g

    const int tid = threadIdx.x;
    const int g = blockIdx.x;
    const long eBase = (long)g * EPG;

    // ---- load x tile (32x16)
    if (tid < PP * FF) sU[tid] = x[g * PP * FF + tid];
    __syncthreads();

    // ---- layer-1 node transforms (K = 16): xl1 -> sA, xr1 -> sB
    // 1024 threads: j = tid&127, 4 rows each.
    {
        const int j = tid & 127, d0 = (tid >> 7) * 4;
        float wl[16], wr[16];
#pragma unroll
        for (int q = 0; q < 4; ++q) {
            *(float4*)(wl + q * 4) = *(const float4*)(W1l + j * FF + q * 4);
            *(float4*)(wr + q * 4) = *(const float4*)(W1r + j * FF + q * 4);
        }
        const float bl = b1l[j], br = b1r[j];
#pragma unroll
        for (int i = 0; i < 4; ++i) {
            const float* xr = sU + (d0 + i) * FF;
            float al = bl, ar = br;
#pragma unroll
            for (int k = 0; k < FF; ++k) {
                const float xv = xr[k];
                al = fmaf(wl[k], xv, al);
                ar = fmaf(wr[k], xv, ar);
            }
            sA[(d0 + i) * DD + j] = al;
            sB[(d0 + i) * DD + j] = ar;
        }
    }
    __syncthreads();

    attention(eattr, W1e, att1, bias1, sA, sB, sU, sH, tid, eBase, false);
    __syncthreads();

    // ---- MeanSubtractionNorm per graph, then ReLU (512 threads, quad/column)
    if (tid < 512) {
        const int col = tid >> 2, r = tid & 3;
        float v[8];
        float ssum = 0.f;
#pragma unroll
        for (int i = 0; i < 8; ++i) {
            v[i] = sH[(r * 8 + i) * DD + col];
            ssum += v[i];
        }
        ssum = redquad(ssum);
        const float mn = ssum * (1.0f / 32.0f);
#pragma unroll
        for (int i = 0; i < 8; ++i)
            sH[(r * 8 + i) * DD + col] = fmaxf(v[i] - mn, 0.f);
    }
    __syncthreads();

    // ---- fused layer-2 node transforms (K = 128): read sH rows ONCE for both
    // W2l and W2r.  1024 threads: jj = tid&127 (one j), d0 = (tid>>7)*4 rows.
    {
        const int jj = tid & 127, d0 = (tid >> 7) * 4;
        float accL[4], accR[4];
        const float bl = b2l[jj], br = b2r[jj];
#pragma unroll
        for (int i = 0; i < 4; ++i) { accL[i] = bl; accR[i] = br; }
        const float* WL = W2l + jj * DD;
        const float* WR = W2r + jj * DD;
        for (int k8 = 0; k8 < 16; ++k8) {
            const float4 l0 = *(const float4*)(WL + k8 * 8), l1 = *(const float4*)(WL + k8 * 8 + 4);
            const float4 r0 = *(const float4*)(WR + k8 * 8), r1 = *(const float4*)(WR + k8 * 8 + 4);
#pragma unroll
            for (int i = 0; i < 4; ++i) {
                const float4 a0 = *(const float4*)(sH + (d0 + i) * DD + k8 * 8);
                const float4 a1 = *(const float4*)(sH + (d0 + i) * DD + k8 * 8 + 4);
                accL[i] = fmaf(l0.x, a0.x, accL[i]); accL[i] = fmaf(l0.y, a0.y, accL[i]);
                accL[i] = fmaf(l0.z, a0.z, accL[i]); accL[i] = fmaf(l0.w, a0.w, accL[i]);
                accL[i] = fmaf(l1.x, a1.x, accL[i]); accL[i] = fmaf(l1.y, a1.y, accL[i]);
                accL[i] = fmaf(l1.z, a1.z, accL[i]); accL[i] = fmaf(l1.w, a1.w, accL[i]);
                accR[i] = fmaf(r0.x, a0.x, accR[i]); accR[i] = fmaf(r0.y, a0.y, accR[i]);
                accR[i] = fmaf(r0.z, a0.z, accR[i]); accR[i] = fmaf(r0.w, a0.w, accR[i]);
                accR[i] = fmaf(r1.x, a1.x, accR[i]); accR[i] = fmaf(r1.y, a1.y, accR[i]);
                accR[i] = fmaf(r1.z, a1.z, accR[i]); accR[i] = fmaf(r1.w, a1.w, accR[i]);
            }
        }
#pragma unroll
        for (int i = 0; i < 4; ++i) {
            sA[(d0 + i) * DD + jj] = accL[i];
            sB[(d0 + i) * DD + jj] = accR[i];
        }
    }
    __syncthreads();

    attention(eattr, W2e, att2, bias2, sA, sB, sU, sH, tid, eBase, true);
    __syncthreads();

    // ---- global mean pool -> sU[0..127] (512 threads, quad per column)
    if (tid < 512) {
        const int col = tid >> 2, r = tid & 3;
        float ssum = 0.f;
#pragma unroll
        for (int i = 0; i < 8; ++i) ssum += sH[(r * 8 + i) * DD + col];
        ssum = redquad(ssum);
        if (r == 0) sU[col] = ssum * (1.0f / 32.0f);
    }
    __syncthreads();

    // ---- heads run concurrently: waves 0-7 source-actor, wave 8 critic, wave 9 noop
    if (tid < 512) {
        // source-actor: fused Ws1-GEMM + Ws2 dot -> logits written directly.
        const int jj = tid & 63, d0 = (tid >> 6) * 4;
        const float b0 = bs1[jj], b1 = bs1[jj + 64];
        float acc0[4], acc1[4];
#pragma unroll
        for (int i = 0; i < 4; ++i) { acc0[i] = b0; acc1[i] = b1; }
        const float* W0 = Ws1 + jj * DD;
        const float* W1 = Ws1 + (jj + 64) * DD;
        for (int k8 = 0; k8 < 16; ++k8) {
            const float4 w00 = *(const float4*)(W0 + k8 * 8), w01 = *(const float4*)(W0 + k8 * 8 + 4);
            const float4 w10 = *(const float4*)(W1 + k8 * 8), w11 = *(const float4*)(W1 + k8 * 8 + 4);
#pragma unroll
            for (int i = 0; i < 4; ++i) {
                const float4 a0 = *(const float4*)(sH + (d0 + i) * DD + k8 * 8);
                const float4 a1 = *(const float4*)(sH + (d0 + i) * DD + k8 * 8 + 4);
                acc0[i] = fmaf(w00.x, a0.x, acc0[i]); acc0[i] = fmaf(w00.y, a0.y, acc0[i]);
                acc0[i] = fmaf(w00.z, a0.z, acc0[i]); acc0[i] = fmaf(w00.w, a0.w, acc0[i]);
                acc0[i] = fmaf(w01.x, a1.x, acc0[i]); acc0[i] = fmaf(w01.y, a1.y, acc0[i]);
                acc0[i] = fmaf(w01.z, a1.z, acc0[i]); acc0[i] = fmaf(w01.w, a1.w, acc0[i]);
                acc1[i] = fmaf(w10.x, a0.x, acc1[i]); acc1[i] = fmaf(w10.y, a0.y, acc1[i]);
                acc1[i] = fmaf(w10.z, a0.z, acc1[i]); acc1[i] = fmaf(w10.w, a0.w, acc1[i]);
                acc1[i] = fmaf(w11.x, a1.x, acc1[i]); acc1[i] = fmaf(w11.y, a1.y, acc1[i]);
                acc1[i] = fmaf(w11.z, a1.z, acc1[i]); acc1[i] = fmaf(w11.w, a1.w, acc1[i]);
            }
        }
        const float ws2a = Ws2[jj], ws2b = Ws2[jj + 64];
        const float bias2s = bs2[0];
#pragma unroll
        for (int i = 0; i < 4; ++i) {
            const float t = fmaf(fmaxf(acc0[i], 0.f), ws2a, fmaxf(acc1[i], 0.f) * ws2b);
            const float r = red64(t);                 // lane 63 holds node logit
            if ((tid & 63) == 63) out[g * 34 + 2 + d0 + i] = r + bias2s;
        }
    } else if (tid < 640) {
        // value / noop: wave 8 = critic, wave 9 = noop (fused hidden + dot)
        const int t = tid - 512;
        const int w = t >> 6, j = t & 63;
        const float* Wa = (w ? Wn1 : Wc1);
        const float* ba = (w ? bn1 : bc1);
        const float* Wb = (w ? Wn2 : Wc2);
        const float  bb = (w ? bn2 : bc2)[0];
        float h0 = ba[j], h1 = ba[j + 64];
        const float* R0 = Wa + j * DD;
        const float* R1 = Wa + (j + 64) * DD;
#pragma unroll
        for (int k8 = 0; k8 < 16; ++k8) {
            const float4 g0 = *(const float4*)(sU + k8 * 8);
            const float4 g1 = *(const float4*)(sU + k8 * 8 + 4);
            const float4 p00 = *(const float4*)(R0 + k8 * 8), p01 = *(const float4*)(R0 + k8 * 8 + 4);
            const float4 p10 = *(const float4*)(R1 + k8 * 8), p11 = *(const float4*)(R1 + k8 * 8 + 4);
            h0 = fmaf(p00.x, g0.x, h0); h0 = fmaf(p00.y, g0.y, h0);
            h0 = fmaf(p00.z, g0.z, h0); h0 = fmaf(p00.w, g0.w, h0);
            h0 = fmaf(p01.x, g1.x, h0); h0 = fmaf(p01.y, g1.y, h0);
            h0 = fmaf(p01.z, g1.z, h0); h0 = fmaf(p01.w, g1.w, h0);
            h1 = fmaf(p10.x, g0.x, h1); h1 = fmaf(p10.y, g0.y, h1);
            h1 = fmaf(p10.z, g0.z, h1); h1 = fmaf(p10.w, g0.w, h1);
            h1 = fmaf(p11.x, g1.x, h1); h1 = fmaf(p11.y, g1.y, h1);
            h1 = fmaf(p11.w, g1.w, h1); h1 = fmaf(p11.z, g1.z, h1);
        }
        const float tt = fmaf(fmaxf(h0, 0.f), Wb[j], fmaxf(h1, 0.f) * Wb[j + 64]);
        const float r = red64(tt);
        if (j == 63) out[g * 34 + w] = r + bb;
    }
}

extern "C" void kernel_launch(void* const* d_in, const int* in_sizes, int n_in,
                              void* d_out, int out_size, void* d_ws, size_t ws_size,
                              hipStream_t stream)
{
    (void)in_sizes; (void)n_in; (void)d_ws; (void)ws_size; (void)out_size;
    // d_in[1] (edge_index) unused: edge structure is analytic (validated R3).
    planetwars_gnn_kernel<<<dim3(NB), dim3(1024), 0, stream>>>(
        (const float*)d_in[0], (const float*)d_in[2],
        (const float*)d_in[3], (const float*)d_in[4], (const float*)d_in[5], (const float*)d_in[6],
        (const float*)d_in[7], (const float*)d_in[8], (const float*)d_in[9],
        (const float*)d_in[10], (const float*)d_in[11], (const float*)d_in[12], (const float*)d_in[13],
        (const float*)d_in[14], (const float*)d_in[15], (const float*)d_in[16],
        (const float*)d_in[17], (const float*)d_in[18], (const float*)d_in[19], (const float*)d_in[20],
        (const float*)d_in[21], (const float*)d_in[22], (const float*)d_in[23], (const float*)d_in[24],
        (const float*)d_in[25], (const float*)d_in[26], (const float*)d_in[27], (const float*)d_in[28],
        (float*)d_out);
}

// Round 3
// 310.810 us; speedup vs baseline: 1.0781x; 1.0781x over previous
//
#include <hip/hip_runtime.h>

#define PP    32      // nodes per graph
#define FF    16      // input features
#define HH    4       // heads
#define CC    32      // head dim
#define DD    128     // hidden (H*C)
#define EDIM  5
#define EPG   992     // edges per graph = P*(P-1)
#define NB    512     // graphs

// ---- DPP helpers (validated R4: ctrl 0x111/2/4/8, 0x142) --------------------
template <int CTRL>
__device__ __forceinline__ float dpp_add(float v) {
    int t = __builtin_amdgcn_update_dpp(0, __builtin_bit_cast(int, v), CTRL, 0xF, 0xF, true);
    return v + __builtin_bit_cast(float, t);
}
template <int CTRL>
__device__ __forceinline__ float dpp_mov(float v) {
    int t = __builtin_amdgcn_update_dpp(0, __builtin_bit_cast(int, v), CTRL, 0xF, 0xF, true);
    return __builtin_bit_cast(float, t);
}
// full 64-lane sum -> result valid in lane 63
__device__ __forceinline__ float red64(float v) {
    v = dpp_add<0x111>(v);   // row_shr:1
    v = dpp_add<0x112>(v);   // row_shr:2
    v = dpp_add<0x114>(v);   // row_shr:4
    v = dpp_add<0x118>(v);   // row_shr:8
    v = dpp_add<0x142>(v);   // row_bcast:15
    v = dpp_add<0x143>(v);   // row_bcast:31
    return v;
}
// quad butterfly sum -> all 4 lanes hold the sum
__device__ __forceinline__ float redquad(float v) {
    v = dpp_add<0xB1>(v);    // quad_perm [1,0,3,2]  (xor 1)
    v = dpp_add<0x4E>(v);    // quad_perm [2,3,0,1]  (xor 2)
    return v;
}
// quad butterfly max -> all 4 lanes hold the max
__device__ __forceinline__ float maxquad(float v) {
    v = fmaxf(v, dpp_mov<0xB1>(v));
    v = fmaxf(v, dpp_mov<0x4E>(v));
    return v;
}
// xor-4 butterfly add via ds_swizzle (BitMode: xor=4, and=0x1F) -> 8-lane sum
// (validated on HW in R2 run)
__device__ __forceinline__ float swz_xor4_add(float v) {
    int t = __builtin_amdgcn_ds_swizzle(__builtin_bit_cast(int, v), 0x101F);
    return v + __builtin_bit_cast(float, t);
}

// ---- GATv2 layer (512-thread block) -----------------------------------------
// Score phase lane map (c8, validated R2): h = (tid>>3)&3, c8 = tid&7,
// ch0 = (tid&31)*4 (4 channels/lane); s = (tid>>5) + half*16, 2-pass s-loop.
// Persistent regs: we[20] + at[4] + xl[4] ~ 28 -> room to software-pipeline.
// d-loop manually unrolled x2 with both edge-attr loads + both xr LDS reads
// issued before either FMA chain (overlaps two ~150cy latencies).
// Head-sum = quad DPP + ds_swizzle xor-4 (8-lane butterfly).
// Diagonal d==s computed with a clamped in-bounds edge and discarded by softmax.
// sS layout: sS[s*128 + d*4 + h].
__device__ __forceinline__ void attention(const float* __restrict__ eattr,
                                          const float* __restrict__ We, const float* __restrict__ att,
                                          const float* __restrict__ bias,
                                          const float* __restrict__ sMsg, const float* __restrict__ sDst,
                                          float* __restrict__ sS, float* __restrict__ sOut,
                                          int tid, long eBase, bool relu)
{
    {
        const int h4  = (tid >> 3) & 3;
        const int c8  = tid & 7;
        const int ch0 = (tid & 31) * 4;               // h*32 + c8*4
        float we[20], at[4];
#pragma unroll
        for (int q = 0; q < 5; ++q)
            *(float4*)(we + q * 4) = *(const float4*)(We + ch0 * EDIM + q * 4);
        *(float4*)(at) = *(const float4*)(att + ch0);

        for (int half = 0; half < 2; ++half) {
            const int s = (tid >> 5) + half * 16;
            float xl[4];
            *(float4*)(xl) = *(const float4*)(sMsg + s * DD + ch0);
            const float* eaRow = eattr + (eBase + (long)s * 31) * EDIM;
            for (int d0 = 0; d0 < PP; d0 += 2) {
                const int d1 = d0 + 1;
                int j0 = d0 - (d0 > s); if (j0 > 30) j0 = 30;   // diag clamp
                int j1 = d1 - (d1 > s); if (j1 > 30) j1 = 30;
                const float* ea0 = eaRow + j0 * EDIM;
                const float* ea1 = eaRow + j1 * EDIM;
                const float e00 = ea0[0], e01 = ea0[1], e02 = ea0[2], e03 = ea0[3], e04 = ea0[4];
                const float e10 = ea1[0], e11 = ea1[1], e12 = ea1[2], e13 = ea1[3], e14 = ea1[4];
                float xr0[4], xr1[4];
                *(float4*)(xr0) = *(const float4*)(sDst + d0 * DD + ch0);
                *(float4*)(xr1) = *(const float4*)(sDst + d1 * DD + ch0);
                float a00 = 0.f, a01 = 0.f, a10 = 0.f, a11 = 0.f;
#pragma unroll
                for (int c = 0; c < 4; ++c) {
                    const float* w = we + c * EDIM;
                    float v0 = xl[c] + xr0[c];
                    v0 = fmaf(w[0], e00, v0); v0 = fmaf(w[1], e01, v0); v0 = fmaf(w[2], e02, v0);
                    v0 = fmaf(w[3], e03, v0); v0 = fmaf(w[4], e04, v0);
                    v0 = fmaf(0.4f, fabsf(v0), 0.6f * v0);      // leaky_relu(., 0.2)
                    float v1 = xl[c] + xr1[c];
                    v1 = fmaf(w[0], e10, v1); v1 = fmaf(w[1], e11, v1); v1 = fmaf(w[2], e12, v1);
                    v1 = fmaf(w[3], e13, v1); v1 = fmaf(w[4], e14, v1);
                    v1 = fmaf(0.4f, fabsf(v1), 0.6f * v1);
                    if (c & 1) { a01 = fmaf(v0, at[c], a01); a11 = fmaf(v1, at[c], a11); }
                    else       { a00 = fmaf(v0, at[c], a00); a10 = fmaf(v1, at[c], a10); }
                }
                const float r0 = swz_xor4_add(redquad(a00 + a01));
                const float r1 = swz_xor4_add(redquad(a10 + a11));
                if (c8 == (d0 & 7)) sS[s * DD + d0 * HH + h4] = r0;
                if (c8 == (d1 & 7)) sS[s * DD + d1 * HH + h4] = r1;
            }
        }
    }
    __syncthreads();
    // ---- segment softmax over s != d per column (d*4+h): all 512 threads,
    // quad per column, r = tid&3 owns 8 rows, DPP quad reduce (validated R1).
    {
        const int col = tid >> 2;
        const int r   = tid & 3;
        const int dd  = col >> 2;                     // destination node of this column
        float v[8];
        float mx = -3.4e38f;
#pragma unroll
        for (int i = 0; i < 8; ++i) {
            const int s = r * 8 + i;
            v[i] = sS[s * DD + col];
            mx = (s == dd) ? mx : fmaxf(mx, v[i]);
        }
        mx = maxquad(mx);
        float sum = 0.f;
#pragma unroll
        for (int i = 0; i < 8; ++i) {
            const int s = r * 8 + i;
            float ex = __expf(v[i] - mx);
            ex = (s == dd) ? 0.f : ex;                // diagonal forced to 0
            v[i] = ex; sum += ex;
        }
        sum = redquad(sum);
        const float inv = 1.f / (sum + 1e-16f);
#pragma unroll
        for (int i = 0; i < 8; ++i)
            sS[(r * 8 + i) * DD + col] = v[i] * inv;
    }
    __syncthreads();
    // ---- aggregation: out[d][ch] = bias[ch] + sum_s alpha[s][d,h(ch)] * msg[s][ch]
    {
        const int d = tid >> 4, sub = tid & 15;
#pragma unroll
        for (int half = 0; half < 2; ++half) {
            const int ch4 = half * 16 + sub;
            const int idx = d * HH + (ch4 >> 3);
            const float* bp = bias + ch4 * 4;
            float4 acc = make_float4(bp[0], bp[1], bp[2], bp[3]);
#pragma unroll
            for (int s = 0; s < PP; ++s) {
                const float a = sS[s * DD + idx];     // alpha(d==s) == 0
                const float4 xv = *(const float4*)(sMsg + s * DD + ch4 * 4);
                acc.x = fmaf(a, xv.x, acc.x);
                acc.y = fmaf(a, xv.y, acc.y);
                acc.z = fmaf(a, xv.z, acc.z);
                acc.w = fmaf(a, xv.w, acc.w);
            }
            if (relu) {
                acc.x = fmaxf(acc.x, 0.f); acc.y = fmaxf(acc.y, 0.f);
                acc.z = fmaxf(acc.z, 0.f); acc.w = fmaxf(acc.w, 0.f);
            }
            *(float4*)(sOut + d * DD + ch4 * 4) = acc;
        }
    }
}

extern "C" __global__ void __launch_bounds__(512, 4)
planetwars_gnn_kernel(const float* __restrict__ x, const float* __restrict__ eattr,
                      const float* __restrict__ W1l, const float* __restrict__ b1l,
                      const float* __restrict__ W1r, const float* __restrict__ b1r,
                      const float* __restrict__ W1e, const float* __restrict__ att1, const float* __restrict__ bias1,
                      const float* __restrict__ W2l, const float* __restrict__ b2l,
                      const float* __restrict__ W2r, const float* __restrict__ b2r,
                      const float* __restrict__ W2e, const float* __restrict__ att2, const float* __restrict__ bias2,
                      const float* __restrict__ Wc1, const float* __restrict__ bc1,
                      const float* __restrict__ Wc2, const float* __restrict__ bc2,
                      const float* __restrict__ Ws1, const float* __restrict__ bs1,
                      const float* __restrict__ Ws2, const float* __restrict__ bs2,
                      const float* __restrict__ Wn1, const float* __restrict__ bn1,
                      const float* __restrict__ Wn2, const float* __restrict__ bn2,
                      float* __restrict__ out)
{
    __shared__ __align__(16) float sA[PP * DD];   // xl1 -> xl2
    __shared__ __align__(16) float sB[PP * DD];   // xr1 -> xr2
    __shared__ __align__(16) float sH[PP * DD];   // h1 -> h2
    __shared__ __align__(16) float sU[PP * DD];   // x | scores/alpha | g

    const int tid = threadIdx.x;
    const int g = blockIdx.x;
    const long eBase = (long)g * EPG;

    // ---- load x tile (32x16), one element per thread
    sU[tid] = x[g * PP * FF + tid];
    __syncthreads();

    // ---- layer-1 node transforms (K = 16): xl1 -> sA, xr1 -> sB
    {
        const int j = tid & 127, d0 = (tid >> 7) * 8;
        float wl[16], wr[16];
#pragma unroll
        for (int q = 0; q < 4; ++q) {
            *(float4*)(wl + q * 4) = *(const float4*)(W1l + j * FF + q * 4);
            *(float4*)(wr + q * 4) = *(const float4*)(W1r + j * FF + q * 4);
        }
        const float bl = b1l[j], br = b1r[j];
#pragma unroll
        for (int i = 0; i < 8; ++i) {
            const float* xr = sU + (d0 + i) * FF;
            float al = bl, ar = br;
#pragma unroll
            for (int k = 0; k < FF; ++k) {
                const float xv = xr[k];
                al = fmaf(wl[k], xv, al);
                ar = fmaf(wr[k], xv, ar);
            }
            sA[(d0 + i) * DD + j] = al;
            sB[(d0 + i) * DD + j] = ar;
        }
    }
    __syncthreads();

    attention(eattr, W1e, att1, bias1, sA, sB, sU, sH, tid, eBase, false);
    __syncthreads();

    // ---- MeanSubtractionNorm per graph, then ReLU (512 threads, quad/column)
    {
        const int col = tid >> 2, r = tid & 3;
        float v[8];
        float ssum = 0.f;
#pragma unroll
        for (int i = 0; i < 8; ++i) {
            v[i] = sH[(r * 8 + i) * DD + col];
            ssum += v[i];
        }
        ssum = redquad(ssum);
        const float mn = ssum * (1.0f / 32.0f);
#pragma unroll
        for (int i = 0; i < 8; ++i)
            sH[(r * 8 + i) * DD + col] = fmaxf(v[i] - mn, 0.f);
    }
    __syncthreads();

    // ---- fused layer-2 node transforms (K = 128): read sH rows ONCE for both
    // W2l and W2r.  jj = tid&63 covers j=jj and j=jj+64; d0 wave-uniform.
    {
        const int jj = tid & 63, d0 = (tid >> 6) * 4;
        float accL0[4], accL1[4], accR0[4], accR1[4];
        const float bl0 = b2l[jj], bl1 = b2l[jj + 64];
        const float br0 = b2r[jj], br1 = b2r[jj + 64];
#pragma unroll
        for (int i = 0; i < 4; ++i) { accL0[i] = bl0; accL1[i] = bl1; accR0[i] = br0; accR1[i] = br1; }
        const float* WL0 = W2l + jj * DD;
        const float* WL1 = W2l + (jj + 64) * DD;
        const float* WR0 = W2r + jj * DD;
        const float* WR1 = W2r + (jj + 64) * DD;
        for (int k8 = 0; k8 < 16; ++k8) {
            const float4 l00 = *(const float4*)(WL0 + k8 * 8), l01 = *(const float4*)(WL0 + k8 * 8 + 4);
            const float4 l10 = *(const float4*)(WL1 + k8 * 8), l11 = *(const float4*)(WL1 + k8 * 8 + 4);
            const float4 r00 = *(const float4*)(WR0 + k8 * 8), r01 = *(const float4*)(WR0 + k8 * 8 + 4);
            const float4 r10 = *(const float4*)(WR1 + k8 * 8), r11 = *(const float4*)(WR1 + k8 * 8 + 4);
#pragma unroll
            for (int i = 0; i < 4; ++i) {
                const float4 a0 = *(const float4*)(sH + (d0 + i) * DD + k8 * 8);
                const float4 a1 = *(const float4*)(sH + (d0 + i) * DD + k8 * 8 + 4);
                accL0[i] = fmaf(l00.x, a0.x, accL0[i]); accL0[i] = fmaf(l00.y, a0.y, accL0[i]);
                accL0[i] = fmaf(l00.z, a0.z, accL0[i]); accL0[i] = fmaf(l00.w, a0.w, accL0[i]);
                accL0[i] = fmaf(l01.x, a1.x, accL0[i]); accL0[i] = fmaf(l01.y, a1.y, accL0[i]);
                accL0[i] = fmaf(l01.z, a1.z, accL0[i]); accL0[i] = fmaf(l01.w, a1.w, accL0[i]);
                accL1[i] = fmaf(l10.x, a0.x, accL1[i]); accL1[i] = fmaf(l10.y, a0.y, accL1[i]);
                accL1[i] = fmaf(l10.z, a0.z, accL1[i]); accL1[i] = fmaf(l10.w, a0.w, accL1[i]);
                accL1[i] = fmaf(l11.x, a1.x, accL1[i]); accL1[i] = fmaf(l11.y, a1.y, accL1[i]);
                accL1[i] = fmaf(l11.z, a1.z, accL1[i]); accL1[i] = fmaf(l11.w, a1.w, accL1[i]);
                accR0[i] = fmaf(r00.x, a0.x, accR0[i]); accR0[i] = fmaf(r00.y, a0.y, accR0[i]);
                accR0[i] = fmaf(r00.z, a0.z, accR0[i]); accR0[i] = fmaf(r00.w, a0.w, accR0[i]);
                accR0[i] = fmaf(r01.x, a1.x, accR0[i]); accR0[i] = fmaf(r01.y, a1.y, accR0[i]);
                accR0[i] = fmaf(r01.z, a1.z, accR0[i]); accR0[i] = fmaf(r01.w, a1.w, accR0[i]);
                accR1[i] = fmaf(r10.x, a0.x, accR1[i]); accR1[i] = fmaf(r10.y, a0.y, accR1[i]);
                accR1[i] = fmaf(r10.z, a0.z, accR1[i]); accR1[i] = fmaf(r10.w, a0.w, accR1[i]);
                accR1[i] = fmaf(r11.x, a1.x, accR1[i]); accR1[i] = fmaf(r11.y, a1.y, accR1[i]);
                accR1[i] = fmaf(r11.z, a1.z, accR1[i]); accR1[i] = fmaf(r11.w, a1.w, accR1[i]);
            }
        }
#pragma unroll
        for (int i = 0; i < 4; ++i) {
            sA[(d0 + i) * DD + jj]      = accL0[i];
            sA[(d0 + i) * DD + jj + 64] = accL1[i];
            sB[(d0 + i) * DD + jj]      = accR0[i];
            sB[(d0 + i) * DD + jj + 64] = accR1[i];
        }
    }
    __syncthreads();

    attention(eattr, W2e, att2, bias2, sA, sB, sU, sH, tid, eBase, true);
    __syncthreads();

    // ---- global mean pool -> sU[0..127] (512 threads, quad per column)
    {
        const int col = tid >> 2, r = tid & 3;
        float ssum = 0.f;
#pragma unroll
        for (int i = 0; i < 8; ++i) ssum += sH[(r * 8 + i) * DD + col];
        ssum = redquad(ssum);
        if (r == 0) sU[col] = ssum * (1.0f / 32.0f);
    }
    __syncthreads();

    // ---- source-actor: fused Ws1-GEMM + Ws2 dot -> logits written directly.
    {
        const int jj = tid & 63, d0 = (tid >> 6) * 4;
        const float b0 = bs1[jj], b1 = bs1[jj + 64];
        float acc0[4], acc1[4];
#pragma unroll
        for (int i = 0; i < 4; ++i) { acc0[i] = b0; acc1[i] = b1; }
        const float* W0 = Ws1 + jj * DD;
        const float* W1 = Ws1 + (jj + 64) * DD;
        for (int k8 = 0; k8 < 16; ++k8) {
            const float4 w00 = *(const float4*)(W0 + k8 * 8), w01 = *(const float4*)(W0 + k8 * 8 + 4);
            const float4 w10 = *(const float4*)(W1 + k8 * 8), w11 = *(const float4*)(W1 + k8 * 8 + 4);
#pragma unroll
            for (int i = 0; i < 4; ++i) {
                const float4 a0 = *(const float4*)(sH + (d0 + i) * DD + k8 * 8);
                const float4 a1 = *(const float4*)(sH + (d0 + i) * DD + k8 * 8 + 4);
                acc0[i] = fmaf(w00.x, a0.x, acc0[i]); acc0[i] = fmaf(w00.y, a0.y, acc0[i]);
                acc0[i] = fmaf(w00.z, a0.z, acc0[i]); acc0[i] = fmaf(w00.w, a0.w, acc0[i]);
                acc0[i] = fmaf(w01.x, a1.x, acc0[i]); acc0[i] = fmaf(w01.y, a1.y, acc0[i]);
                acc0[i] = fmaf(w01.z, a1.z, acc0[i]); acc0[i] = fmaf(w01.w, a1.w, acc0[i]);
                acc1[i] = fmaf(w10.x, a0.x, acc1[i]); acc1[i] = fmaf(w10.y, a0.y, acc1[i]);
                acc1[i] = fmaf(w10.z, a0.z, acc1[i]); acc1[i] = fmaf(w10.w, a0.w, acc1[i]);
                acc1[i] = fmaf(w11.x, a1.x, acc1[i]); acc1[i] = fmaf(w11.y, a1.y, acc1[i]);
                acc1[i] = fmaf(w11.z, a1.z, acc1[i]); acc1[i] = fmaf(w11.w, a1.w, acc1[i]);
            }
        }
        const float ws2a = Ws2[jj], ws2b = Ws2[jj + 64];
        const float bias2s = bs2[0];
#pragma unroll
        for (int i = 0; i < 4; ++i) {
            const float t = fmaf(fmaxf(acc0[i], 0.f), ws2a, fmaxf(acc1[i], 0.f) * ws2b);
            const float r = red64(t);                 // lane 63 holds node logit
            if ((tid & 63) == 63) out[g * 34 + 2 + d0 + i] = r + bias2s;
        }
    }

    // ---- value / noop: wave 0 = critic, wave 1 = noop (fused hidden + dot)
    if (tid < 128) {
        const int w = tid >> 6, j = tid & 63;
        const float* Wa = (w ? Wn1 : Wc1);
        const float* ba = (w ? bn1 : bc1);
        const float* Wb = (w ? Wn2 : Wc2);
        const float  bb = (w ? bn2 : bc2)[0];
        float h0 = ba[j], h1 = ba[j + 64];
        const float* R0 = Wa + j * DD;
        const float* R1 = Wa + (j + 64) * DD;
#pragma unroll
        for (int k8 = 0; k8 < 16; ++k8) {
            const float4 g0 = *(const float4*)(sU + k8 * 8);
            const float4 g1 = *(const float4*)(sU + k8 * 8 + 4);
            const float4 p00 = *(const float4*)(R0 + k8 * 8), p01 = *(const float4*)(R0 + k8 * 8 + 4);
            const float4 p10 = *(const float4*)(R1 + k8 * 8), p11 = *(const float4*)(R1 + k8 * 8 + 4);
            h0 = fmaf(p00.x, g0.x, h0); h0 = fmaf(p00.y, g0.y, h0);
            h0 = fmaf(p00.z, g0.z, h0); h0 = fmaf(p00.w, g0.w, h0);
            h0 = fmaf(p01.x, g1.x, h0); h0 = fmaf(p01.y, g1.y, h0);
            h0 = fmaf(p01.z, g1.z, h0); h0 = fmaf(p01.w, g1.w, h0);
            h1 = fmaf(p10.x, g0.x, h1); h1 = fmaf(p10.y, g0.y, h1);
            h1 = fmaf(p10.z, g0.z, h1); h1 = fmaf(p10.w, g0.w, h1);
            h1 = fmaf(p11.x, g1.x, h1); h1 = fmaf(p11.y, g1.y, h1);
            h1 = fmaf(p11.z, g1.z, h1); h1 = fmaf(p11.w, g1.w, h1);
        }
        const float t = fmaf(fmaxf(h0, 0.f), Wb[j], fmaxf(h1, 0.f) * Wb[j + 64]);
        const float r = red64(t);
        if (j == 63) out[g * 34 + w] = r + bb;
    }
}

extern "C" void kernel_launch(void* const* d_in, const int* in_sizes, int n_in,
                              void* d_out, int out_size, void* d_ws, size_t ws_size,
                              hipStream_t stream)
{
    (void)in_sizes; (void)n_in; (void)d_ws; (void)ws_size; (void)out_size;
    // d_in[1] (edge_index) unused: edge structure is analytic (validated R3).
    planetwars_gnn_kernel<<<dim3(NB), dim3(512), 0, stream>>>(
        (const float*)d_in[0], (const float*)d_in[2],
        (const float*)d_in[3], (const float*)d_in[4], (const float*)d_in[5], (const float*)d_in[6],
        (const float*)d_in[7], (const float*)d_in[8], (const float*)d_in[9],
        (const float*)d_in[10], (const float*)d_in[11], (const float*)d_in[12], (const float*)d_in[13],
        (const float*)d_in[14], (const float*)d_in[15], (const float*)d_in[16],
        (const float*)d_in[17], (const float*)d_in[18], (const float*)d_in[19], (const float*)d_in[20],
        (const float*)d_in[21], (const float*)d_in[22], (const float*)d_in[23], (const float*)d_in[24],
        (const float*)d_in[25], (const float*)d_in[26], (const float*)d_in[27], (const float*)d_in[28],
        (float*)d_out);
}

// Round 4
// 243.717 us; speedup vs baseline: 1.3749x; 1.2753x over previous
//
#include <hip/hip_runtime.h>

#define PP    32      // nodes per graph
#define FF    16      // input features
#define HH    4       // heads
#define CC    32      // head dim
#define DD    128     // hidden (H*C)
#define EDIM  5
#define EPG   992     // edges per graph = P*(P-1)
#define NB    512     // graphs

// ---- DPP helpers (validated R4: ctrl 0x111/2/4/8, 0x142) --------------------
template <int CTRL>
__device__ __forceinline__ float dpp_add(float v) {
    int t = __builtin_amdgcn_update_dpp(0, __builtin_bit_cast(int, v), CTRL, 0xF, 0xF, true);
    return v + __builtin_bit_cast(float, t);
}
template <int CTRL>
__device__ __forceinline__ float dpp_mov(float v) {
    int t = __builtin_amdgcn_update_dpp(0, __builtin_bit_cast(int, v), CTRL, 0xF, 0xF, true);
    return __builtin_bit_cast(float, t);
}
// full 64-lane sum -> result valid in lane 63
__device__ __forceinline__ float red64(float v) {
    v = dpp_add<0x111>(v);   // row_shr:1
    v = dpp_add<0x112>(v);   // row_shr:2
    v = dpp_add<0x114>(v);   // row_shr:4
    v = dpp_add<0x118>(v);   // row_shr:8
    v = dpp_add<0x142>(v);   // row_bcast:15
    v = dpp_add<0x143>(v);   // row_bcast:31
    return v;
}
// quad butterfly sum -> all 4 lanes hold the sum
__device__ __forceinline__ float redquad(float v) {
    v = dpp_add<0xB1>(v);    // quad_perm [1,0,3,2]  (xor 1)
    v = dpp_add<0x4E>(v);    // quad_perm [2,3,0,1]  (xor 2)
    return v;
}
// quad butterfly max -> all 4 lanes hold the max
__device__ __forceinline__ float maxquad(float v) {
    v = fmaxf(v, dpp_mov<0xB1>(v));
    v = fmaxf(v, dpp_mov<0x4E>(v));
    return v;
}

// ---- GATv2 layer ------------------------------------------------------------
// Score phase lane map (baseline, 155us-proven): s = tid>>4, h = (tid>>2)&3,
// c4 = tid&3, ch0 = (tid&15)*8.  Edge attrs are STAGED INTO LDS (sE == sOut,
// dead during the score phase) in two d-halves of 32x16 edges padded to 8
// floats (exactly 16 KB).  The d-loop then reads them via 16-lane broadcast
// LDS loads — no global loads, no index math, no extra register state.
// Diagonal d==s staged from a clamped in-bounds edge and discarded by softmax.
// sS layout: sS[s*128 + d*4 + h].
__device__ __forceinline__ void attention(const float* __restrict__ eattr,
                                          const float* __restrict__ We, const float* __restrict__ att,
                                          const float* __restrict__ bias,
                                          const float* __restrict__ sMsg, const float* __restrict__ sDst,
                                          float* __restrict__ sS, float* __restrict__ sOut,
                                          int tid, long eBase, bool relu)
{
    float* __restrict__ sE = sOut;                    // staging alias (dead until aggregation)
    {
        const int s  = tid >> 4;
        const int ch0 = (tid & 15) * 8;               // h*32 + c4*8
        // preload We[ch0..ch0+7][0..4] (40 consecutive floats), att, xl
        float we[40], at[8], xl[8];
#pragma unroll
        for (int q = 0; q < 10; ++q)
            *(float4*)(we + q * 4) = *(const float4*)(We + ch0 * EDIM + q * 4);
        *(float4*)(at)     = *(const float4*)(att + ch0);
        *(float4*)(at + 4) = *(const float4*)(att + ch0 + 4);
        *(float4*)(xl)     = *(const float4*)(sMsg + s * DD + ch0);
        *(float4*)(xl + 4) = *(const float4*)(sMsg + s * DD + ch0 + 4);

        for (int halfd = 0; halfd < 2; ++halfd) {
            const int d0 = halfd * 16;
            // ---- stage edges (s, d0 + dl): one edge per thread (32s x 16d)
            {
                const int dl = tid & 15;
                const int d = d0 + dl;
                int jj = d - (d > s);
                if (jj > 30) jj = 30;                 // d==s==31 clamp (discarded)
                const float* ea = eattr + (eBase + s * 31 + jj) * EDIM;
                const float e0 = ea[0], e1 = ea[1], e2 = ea[2], e3 = ea[3], e4 = ea[4];
                float* p = sE + (((s << 4) | dl) << 3);
                *(float4*)p = make_float4(e0, e1, e2, e3);
                p[4] = e4;
            }
            __syncthreads();
            // ---- score loop over this d-half: LDS broadcast reads only
            for (int dl = 0; dl < 16; ++dl) {
                const int d = d0 + dl;
                const float* ep = sE + (((s << 4) | dl) << 3);
                const float4 ef = *(const float4*)ep;
                const float e4v = ep[4];
                float xr[8];
                *(float4*)(xr)     = *(const float4*)(sDst + d * DD + ch0);
                *(float4*)(xr + 4) = *(const float4*)(sDst + d * DD + ch0 + 4);
                float acc0 = 0.f, acc1 = 0.f;
#pragma unroll
                for (int c = 0; c < 8; ++c) {
                    float v = xl[c] + xr[c];
                    const float* w = we + c * EDIM;
                    v = fmaf(w[0], ef.x, v); v = fmaf(w[1], ef.y, v); v = fmaf(w[2], ef.z, v);
                    v = fmaf(w[3], ef.w, v); v = fmaf(w[4], e4v, v);
                    v = fmaf(0.4f, fabsf(v), 0.6f * v);   // leaky_relu(., 0.2)
                    if (c & 1) acc1 = fmaf(v, at[c], acc1);
                    else       acc0 = fmaf(v, at[c], acc0);
                }
                const float r = redquad(acc0 + acc1);     // sum over 4 c4-chunks
                if ((tid & 3) == 0)
                    sS[s * DD + d * HH + ((tid >> 2) & 3)] = r;
            }
            __syncthreads();                              // sE half consumed
        }
    }
    // ---- segment softmax over s != d per column (d*4+h): all 512 threads,
    // quad per column, r = tid&3 owns 8 rows, DPP quad reduce (validated R3).
    {
        const int col = tid >> 2;
        const int r   = tid & 3;
        const int dd  = col >> 2;                     // destination node of this column
        float v[8];
        float mx = -3.4e38f;
#pragma unroll
        for (int i = 0; i < 8; ++i) {
            const int s = r * 8 + i;
            v[i] = sS[s * DD + col];
            mx = (s == dd) ? mx : fmaxf(mx, v[i]);
        }
        mx = maxquad(mx);
        float sum = 0.f;
#pragma unroll
        for (int i = 0; i < 8; ++i) {
            const int s = r * 8 + i;
            float ex = __expf(v[i] - mx);
            ex = (s == dd) ? 0.f : ex;                // diagonal forced to 0
            v[i] = ex; sum += ex;
        }
        sum = redquad(sum);
        const float inv = 1.f / (sum + 1e-16f);
#pragma unroll
        for (int i = 0; i < 8; ++i)
            sS[(r * 8 + i) * DD + col] = v[i] * inv;
    }
    __syncthreads();
    // ---- aggregation: out[d][ch] = bias[ch] + sum_s alpha[s][d,h(ch)] * msg[s][ch]
    {
        const int d = tid >> 4, sub = tid & 15;
#pragma unroll
        for (int half = 0; half < 2; ++half) {
            const int ch4 = half * 16 + sub;
            const int idx = d * HH + (ch4 >> 3);
            const float* bp = bias + ch4 * 4;
            float4 acc = make_float4(bp[0], bp[1], bp[2], bp[3]);
#pragma unroll
            for (int s = 0; s < PP; ++s) {
                const float a = sS[s * DD + idx];     // alpha(d==s) == 0
                const float4 xv = *(const float4*)(sMsg + s * DD + ch4 * 4);
                acc.x = fmaf(a, xv.x, acc.x);
                acc.y = fmaf(a, xv.y, acc.y);
                acc.z = fmaf(a, xv.z, acc.z);
                acc.w = fmaf(a, xv.w, acc.w);
            }
            if (relu) {
                acc.x = fmaxf(acc.x, 0.f); acc.y = fmaxf(acc.y, 0.f);
                acc.z = fmaxf(acc.z, 0.f); acc.w = fmaxf(acc.w, 0.f);
            }
            *(float4*)(sOut + d * DD + ch4 * 4) = acc;
        }
    }
}

extern "C" __global__ void __launch_bounds__(512, 4)
planetwars_gnn_kernel(const float* __restrict__ x, const float* __restrict__ eattr,
                      const float* __restrict__ W1l, const float* __restrict__ b1l,
                      const float* __restrict__ W1r, const float* __restrict__ b1r,
                      const float* __restrict__ W1e, const float* __restrict__ att1, const float* __restrict__ bias1,
                      const float* __restrict__ W2l, const float* __restrict__ b2l,
                      const float* __restrict__ W2r, const float* __restrict__ b2r,
                      const float* __restrict__ W2e, const float* __restrict__ att2, const float* __restrict__ bias2,
                      const float* __restrict__ Wc1, const float* __restrict__ bc1,
                      const float* __restrict__ Wc2, const float* __restrict__ bc2,
                      const float* __restrict__ Ws1, const float* __restrict__ bs1,
                      const float* __restrict__ Ws2, const float* __restrict__ bs2,
                      const float* __restrict__ Wn1, const float* __restrict__ bn1,
                      const float* __restrict__ Wn2, const float* __restrict__ bn2,
                      float* __restrict__ out)
{
    __shared__ __align__(16) float sA[PP * DD];   // xl1 -> xl2
    __shared__ __align__(16) float sB[PP * DD];   // xr1 -> xr2
    __shared__ __align__(16) float sH[PP * DD];   // edge staging | h1 -> h2
    __shared__ __align__(16) float sU[PP * DD];   // x | scores/alpha | g

    const int tid = threadIdx.x;
    const int g = blockIdx.x;
    const long eBase = (long)g * EPG;

    // ---- load x tile (32x16), one element per thread
    sU[tid] = x[g * PP * FF + tid];
    __syncthreads();

    // ---- layer-1 node transforms (K = 16): xl1 -> sA, xr1 -> sB
    {
        const int j = tid & 127, d0 = (tid >> 7) * 8;
        float wl[16], wr[16];
#pragma unroll
        for (int q = 0; q < 4; ++q) {
            *(float4*)(wl + q * 4) = *(const float4*)(W1l + j * FF + q * 4);
            *(float4*)(wr + q * 4) = *(const float4*)(W1r + j * FF + q * 4);
        }
        const float bl = b1l[j], br = b1r[j];
#pragma unroll
        for (int i = 0; i < 8; ++i) {
            const float* xr = sU + (d0 + i) * FF;
            float al = bl, ar = br;
#pragma unroll
            for (int k = 0; k < FF; ++k) {
                const float xv = xr[k];
                al = fmaf(wl[k], xv, al);
                ar = fmaf(wr[k], xv, ar);
            }
            sA[(d0 + i) * DD + j] = al;
            sB[(d0 + i) * DD + j] = ar;
        }
    }
    __syncthreads();

    attention(eattr, W1e, att1, bias1, sA, sB, sU, sH, tid, eBase, false);
    __syncthreads();

    // ---- MeanSubtractionNorm per graph, then ReLU (512 threads, quad/column,
    // validated R3)
    {
        const int col = tid >> 2, r = tid & 3;
        float v[8];
        float ssum = 0.f;
#pragma unroll
        for (int i = 0; i < 8; ++i) {
            v[i] = sH[(r * 8 + i) * DD + col];
            ssum += v[i];
        }
        ssum = redquad(ssum);
        const float mn = ssum * (1.0f / 32.0f);
#pragma unroll
        for (int i = 0; i < 8; ++i)
            sH[(r * 8 + i) * DD + col] = fmaxf(v[i] - mn, 0.f);
    }
    __syncthreads();

    // ---- fused layer-2 node transforms (K = 128): read sH rows ONCE for both
    // W2l and W2r.  jj = tid&63 covers j=jj and j=jj+64; d0 wave-uniform.
    {
        const int jj = tid & 63, d0 = (tid >> 6) * 4;
        float accL0[4], accL1[4], accR0[4], accR1[4];
        const float bl0 = b2l[jj], bl1 = b2l[jj + 64];
        const float br0 = b2r[jj], br1 = b2r[jj + 64];
#pragma unroll
        for (int i = 0; i < 4; ++i) { accL0[i] = bl0; accL1[i] = bl1; accR0[i] = br0; accR1[i] = br1; }
        const float* WL0 = W2l + jj * DD;
        const float* WL1 = W2l + (jj + 64) * DD;
        const float* WR0 = W2r + jj * DD;
        const float* WR1 = W2r + (jj + 64) * DD;
        for (int k8 = 0; k8 < 16; ++k8) {
            const float4 l00 = *(const float4*)(WL0 + k8 * 8), l01 = *(const float4*)(WL0 + k8 * 8 + 4);
            const float4 l10 = *(const float4*)(WL1 + k8 * 8), l11 = *(const float4*)(WL1 + k8 * 8 + 4);
            const float4 r00 = *(const float4*)(WR0 + k8 * 8), r01 = *(const float4*)(WR0 + k8 * 8 + 4);
            const float4 r10 = *(const float4*)(WR1 + k8 * 8), r11 = *(const float4*)(WR1 + k8 * 8 + 4);
#pragma unroll
            for (int i = 0; i < 4; ++i) {
                const float4 a0 = *(const float4*)(sH + (d0 + i) * DD + k8 * 8);
                const float4 a1 = *(const float4*)(sH + (d0 + i) * DD + k8 * 8 + 4);
                accL0[i] = fmaf(l00.x, a0.x, accL0[i]); accL0[i] = fmaf(l00.y, a0.y, accL0[i]);
                accL0[i] = fmaf(l00.z, a0.z, accL0[i]); accL0[i] = fmaf(l00.w, a0.w, accL0[i]);
                accL0[i] = fmaf(l01.x, a1.x, accL0[i]); accL0[i] = fmaf(l01.y, a1.y, accL0[i]);
                accL0[i] = fmaf(l01.z, a1.z, accL0[i]); accL0[i] = fmaf(l01.w, a1.w, accL0[i]);
                accL1[i] = fmaf(l10.x, a0.x, accL1[i]); accL1[i] = fmaf(l10.y, a0.y, accL1[i]);
                accL1[i] = fmaf(l10.z, a0.z, accL1[i]); accL1[i] = fmaf(l10.w, a0.w, accL1[i]);
                accL1[i] = fmaf(l11.x, a1.x, accL1[i]); accL1[i] = fmaf(l11.y, a1.y, accL1[i]);
                accL1[i] = fmaf(l11.z, a1.z, accL1[i]); accL1[i] = fmaf(l11.w, a1.w, accL1[i]);
                accR0[i] = fmaf(r00.x, a0.x, accR0[i]); accR0[i] = fmaf(r00.y, a0.y, accR0[i]);
                accR0[i] = fmaf(r00.z, a0.z, accR0[i]); accR0[i] = fmaf(r00.w, a0.w, accR0[i]);
                accR0[i] = fmaf(r01.x, a1.x, accR0[i]); accR0[i] = fmaf(r01.y, a1.y, accR0[i]);
                accR0[i] = fmaf(r01.z, a1.z, accR0[i]); accR0[i] = fmaf(r01.w, a1.w, accR0[i]);
                accR1[i] = fmaf(r10.x, a0.x, accR1[i]); accR1[i] = fmaf(r10.y, a0.y, accR1[i]);
                accR1[i] = fmaf(r10.z, a0.z, accR1[i]); accR1[i] = fmaf(r10.w, a0.w, accR1[i]);
                accR1[i] = fmaf(r11.x, a1.x, accR1[i]); accR1[i] = fmaf(r11.y, a1.y, accR1[i]);
                accR1[i] = fmaf(r11.z, a1.z, accR1[i]); accR1[i] = fmaf(r11.w, a1.w, accR1[i]);
            }
        }
#pragma unroll
        for (int i = 0; i < 4; ++i) {
            sA[(d0 + i) * DD + jj]      = accL0[i];
            sA[(d0 + i) * DD + jj + 64] = accL1[i];
            sB[(d0 + i) * DD + jj]      = accR0[i];
            sB[(d0 + i) * DD + jj + 64] = accR1[i];
        }
    }
    __syncthreads();

    attention(eattr, W2e, att2, bias2, sA, sB, sU, sH, tid, eBase, true);
    __syncthreads();

    // ---- global mean pool -> sU[0..127] (512 threads, quad per column,
    // validated R3)
    {
        const int col = tid >> 2, r = tid & 3;
        float ssum = 0.f;
#pragma unroll
        for (int i = 0; i < 8; ++i) ssum += sH[(r * 8 + i) * DD + col];
        ssum = redquad(ssum);
        if (r == 0) sU[col] = ssum * (1.0f / 32.0f);
    }
    __syncthreads();

    // ---- source-actor: fused Ws1-GEMM + Ws2 dot -> logits written directly.
    {
        const int jj = tid & 63, d0 = (tid >> 6) * 4;
        const float b0 = bs1[jj], b1 = bs1[jj + 64];
        float acc0[4], acc1[4];
#pragma unroll
        for (int i = 0; i < 4; ++i) { acc0[i] = b0; acc1[i] = b1; }
        const float* W0 = Ws1 + jj * DD;
        const float* W1 = Ws1 + (jj + 64) * DD;
        for (int k8 = 0; k8 < 16; ++k8) {
            const float4 w00 = *(const float4*)(W0 + k8 * 8), w01 = *(const float4*)(W0 + k8 * 8 + 4);
            const float4 w10 = *(const float4*)(W1 + k8 * 8), w11 = *(const float4*)(W1 + k8 * 8 + 4);
#pragma unroll
            for (int i = 0; i < 4; ++i) {
                const float4 a0 = *(const float4*)(sH + (d0 + i) * DD + k8 * 8);
                const float4 a1 = *(const float4*)(sH + (d0 + i) * DD + k8 * 8 + 4);
                acc0[i] = fmaf(w00.x, a0.x, acc0[i]); acc0[i] = fmaf(w00.y, a0.y, acc0[i]);
                acc0[i] = fmaf(w00.z, a0.z, acc0[i]); acc0[i] = fmaf(w00.w, a0.w, acc0[i]);
                acc0[i] = fmaf(w01.x, a1.x, acc0[i]); acc0[i] = fmaf(w01.y, a1.y, acc0[i]);
                acc0[i] = fmaf(w01.z, a1.z, acc0[i]); acc0[i] = fmaf(w01.w, a1.w, acc0[i]);
                acc1[i] = fmaf(w10.x, a0.x, acc1[i]); acc1[i] = fmaf(w10.y, a0.y, acc1[i]);
                acc1[i] = fmaf(w10.z, a0.z, acc1[i]); acc1[i] = fmaf(w10.w, a0.w, acc1[i]);
                acc1[i] = fmaf(w11.x, a1.x, acc1[i]); acc1[i] = fmaf(w11.y, a1.y, acc1[i]);
                acc1[i] = fmaf(w11.z, a1.z, acc1[i]); acc1[i] = fmaf(w11.w, a1.w, acc1[i]);
            }
        }
        const float ws2a = Ws2[jj], ws2b = Ws2[jj + 64];
        const float bias2s = bs2[0];
#pragma unroll
        for (int i = 0; i < 4; ++i) {
            const float t = fmaf(fmaxf(acc0[i], 0.f), ws2a, fmaxf(acc1[i], 0.f) * ws2b);
            const float r = red64(t);                 // lane 63 holds node logit
            if ((tid & 63) == 63) out[g * 34 + 2 + d0 + i] = r + bias2s;
        }
    }

    // ---- value / noop: wave 0 = critic, wave 1 = noop (fused hidden + dot)
    if (tid < 128) {
        const int w = tid >> 6, j = tid & 63;
        const float* Wa = (w ? Wn1 : Wc1);
        const float* ba = (w ? bn1 : bc1);
        const float* Wb = (w ? Wn2 : Wc2);
        const float  bb = (w ? bn2 : bc2)[0];
        float h0 = ba[j], h1 = ba[j + 64];
        const float* R0 = Wa + j * DD;
        const float* R1 = Wa + (j + 64) * DD;
#pragma unroll
        for (int k8 = 0; k8 < 16; ++k8) {
            const float4 g0 = *(const float4*)(sU + k8 * 8);
            const float4 g1 = *(const float4*)(sU + k8 * 8 + 4);
            const float4 p00 = *(const float4*)(R0 + k8 * 8), p01 = *(const float4*)(R0 + k8 * 8 + 4);
            const float4 p10 = *(const float4*)(R1 + k8 * 8), p11 = *(const float4*)(R1 + k8 * 8 + 4);
            h0 = fmaf(p00.x, g0.x, h0); h0 = fmaf(p00.y, g0.y, h0);
            h0 = fmaf(p00.z, g0.z, h0); h0 = fmaf(p00.w, g0.w, h0);
            h0 = fmaf(p01.x, g1.x, h0); h0 = fmaf(p01.y, g1.y, h0);
            h0 = fmaf(p01.z, g1.z, h0); h0 = fmaf(p01.w, g1.w, h0);
            h1 = fmaf(p10.x, g0.x, h1); h1 = fmaf(p10.y, g0.y, h1);
            h1 = fmaf(p10.z, g0.z, h1); h1 = fmaf(p10.w, g0.w, h1);
            h1 = fmaf(p11.x, g1.x, h1); h1 = fmaf(p11.y, g1.y, h1);
            h1 = fmaf(p11.z, g1.z, h1); h1 = fmaf(p11.w, g1.w, h1);
        }
        const float t = fmaf(fmaxf(h0, 0.f), Wb[j], fmaxf(h1, 0.f) * Wb[j + 64]);
        const float r = red64(t);
        if (j == 63) out[g * 34 + w] = r + bb;
    }
}

extern "C" void kernel_launch(void* const* d_in, const int* in_sizes, int n_in,
                              void* d_out, int out_size, void* d_ws, size_t ws_size,
                              hipStream_t stream)
{
    (void)in_sizes; (void)n_in; (void)d_ws; (void)ws_size; (void)out_size;
    // d_in[1] (edge_index) unused: edge structure is analytic (validated R3).
    planetwars_gnn_kernel<<<dim3(NB), dim3(512), 0, stream>>>(
        (const float*)d_in[0], (const float*)d_in[2],
        (const float*)d_in[3], (const float*)d_in[4], (const float*)d_in[5], (const float*)d_in[6],
        (const float*)d_in[7], (const float*)d_in[8], (const float*)d_in[9],
        (const float*)d_in[10], (const float*)d_in[11], (const float*)d_in[12], (const float*)d_in[13],
        (const float*)d_in[14], (const float*)d_in[15], (const float*)d_in[16],
        (const float*)d_in[17], (const float*)d_in[18], (const float*)d_in[19], (const float*)d_in[20],
        (const float*)d_in[21], (const float*)d_in[22], (const float*)d_in[23], (const float*)d_in[24],
        (const float*)d_in[25], (const float*)d_in[26], (const float*)d_in[27], (const float*)d_in[28],
        (float*)d_out);
}